// Round 1
// baseline (2200.312 us; speedup 1.0000x reference)
//
#include <hip/hip_runtime.h>

#define N_NODES 50000
#define IN_F 64
#define HIDDEN 512
#define N_EDGES 160000
#define N_TRAIN 80000
#define N_CLASS 7
#define BN_EPS 1e-5f

// ---------------------------------------------------------------------------
// out[i] = (1 + *epsp) * in[i]   (float4 grid-stride-free, n4 = n/4)
// Seeds the GIN aggregation buffer so edge atomics can add straight into it.
// ---------------------------------------------------------------------------
__global__ void scale_init_kernel(const float* __restrict__ in,
                                  const float* __restrict__ epsp,
                                  float* __restrict__ out, int n4) {
    int i = blockIdx.x * blockDim.x + threadIdx.x;
    if (i >= n4) return;
    float s = 1.0f + *epsp;
    float4 v = ((const float4*)in)[i];
    float4 o;
    o.x = s * v.x; o.y = s * v.y; o.z = s * v.z; o.w = s * v.w;
    ((float4*)out)[i] = o;
}

// ---------------------------------------------------------------------------
// agg[dst][f] += h[src][f] over all edges. One thread per (edge, feature).
// logF = log2(F) (F = 64 or 512). Reads coalesced along f; atomics scatter.
// ---------------------------------------------------------------------------
__global__ void edge_agg_kernel(const float* __restrict__ h,
                                const int* __restrict__ ei,
                                float* __restrict__ agg, int logF) {
    int gid = blockIdx.x * blockDim.x + threadIdx.x;
    int F = 1 << logF;
    int total = N_EDGES << logF;
    if (gid >= total) return;
    int e = gid >> logF;
    int f = gid & (F - 1);
    int src = ei[e];
    int dst = ei[N_EDGES + e];
    atomicAdd(&agg[dst * F + f], h[src * F + f]);
}

// ---------------------------------------------------------------------------
// C = epilogue(A @ B + bias). A: MxK row-major, B: KxN row-major, N == 512.
// mode 0: none, 1: relu, 2: relu then batchnorm (inference form).
// Tile 128x64, BK=32, 256 threads, 8x4 micro-tile per thread.
// A stored transposed in LDS (As[k][m], +4 pad keeps float4 alignment).
// ---------------------------------------------------------------------------
#define BM 128
#define BN 64
#define BK 32

__global__ __launch_bounds__(256) void gemm_kernel(
    const float* __restrict__ A, const float* __restrict__ B,
    const float* __restrict__ bias, float* __restrict__ C,
    int M, int K, int mode,
    const float* __restrict__ bn_g, const float* __restrict__ bn_b,
    const float* __restrict__ bn_m, const float* __restrict__ bn_v) {
    const int N = HIDDEN;
    __shared__ float As[BK][BM + 4];
    __shared__ float Bs[BK][BN];

    int tid = threadIdx.x;
    int tx = tid & 15;     // 0..15 along N (4 cols each)
    int ty = tid >> 4;     // 0..15 along M (8 rows each)
    int m0 = blockIdx.x * BM;
    int n0 = blockIdx.y * BN;

    int aRow = tid >> 3;         // 0..31
    int aCol = (tid & 7) * 4;    // 0..28
    int bRow = tid >> 4;         // 0..15
    int bCol = (tid & 15) * 4;   // 0..60

    float acc[8][4];
#pragma unroll
    for (int i = 0; i < 8; i++)
#pragma unroll
        for (int j = 0; j < 4; j++) acc[i][j] = 0.0f;

    for (int k0 = 0; k0 < K; k0 += BK) {
        // stage A tile (transposed into LDS)
#pragma unroll
        for (int r = 0; r < 4; r++) {
            int rl = aRow + r * 32;
            int grow = m0 + rl;
            float4 v = make_float4(0.f, 0.f, 0.f, 0.f);
            if (grow < M) v = *(const float4*)&A[(size_t)grow * K + k0 + aCol];
            As[aCol + 0][rl] = v.x;
            As[aCol + 1][rl] = v.y;
            As[aCol + 2][rl] = v.z;
            As[aCol + 3][rl] = v.w;
        }
        // stage B tile
#pragma unroll
        for (int r = 0; r < 2; r++) {
            int krow = bRow + r * 16;
            *(float4*)&Bs[krow][bCol] =
                *(const float4*)&B[(size_t)(k0 + krow) * N + n0 + bCol];
        }
        __syncthreads();

#pragma unroll
        for (int k = 0; k < BK; k++) {
            float4 a0 = *(const float4*)&As[k][ty * 8];
            float4 a1 = *(const float4*)&As[k][ty * 8 + 4];
            float4 b4 = *(const float4*)&Bs[k][tx * 4];
            float a[8] = {a0.x, a0.y, a0.z, a0.w, a1.x, a1.y, a1.z, a1.w};
            float b[4] = {b4.x, b4.y, b4.z, b4.w};
#pragma unroll
            for (int i = 0; i < 8; i++)
#pragma unroll
                for (int j = 0; j < 4; j++) acc[i][j] = fmaf(a[i], b[j], acc[i][j]);
        }
        __syncthreads();
    }

    // epilogue
    int col = n0 + tx * 4;
    float4 bi = *(const float4*)&bias[col];
    float sc[4] = {1.f, 1.f, 1.f, 1.f}, sh[4] = {0.f, 0.f, 0.f, 0.f};
    if (mode == 2) {
        float4 g = *(const float4*)&bn_g[col];
        float4 bb = *(const float4*)&bn_b[col];
        float4 mm = *(const float4*)&bn_m[col];
        float4 vv = *(const float4*)&bn_v[col];
        sc[0] = g.x * rsqrtf(vv.x + BN_EPS);
        sc[1] = g.y * rsqrtf(vv.y + BN_EPS);
        sc[2] = g.z * rsqrtf(vv.z + BN_EPS);
        sc[3] = g.w * rsqrtf(vv.w + BN_EPS);
        sh[0] = bb.x - mm.x * sc[0];
        sh[1] = bb.y - mm.y * sc[1];
        sh[2] = bb.z - mm.z * sc[2];
        sh[3] = bb.w - mm.w * sc[3];
    }
    float bia[4] = {bi.x, bi.y, bi.z, bi.w};
#pragma unroll
    for (int i = 0; i < 8; i++) {
        int row = m0 + ty * 8 + i;
        if (row >= M) continue;
        float o[4];
#pragma unroll
        for (int j = 0; j < 4; j++) {
            float v = acc[i][j] + bia[j];
            if (mode >= 1) v = fmaxf(v, 0.f);
            if (mode == 2) v = v * sc[j] + sh[j];
            o[j] = v;
        }
        float4 ov = make_float4(o[0], o[1], o[2], o[3]);
        *(float4*)&C[(size_t)row * N + col] = ov;
    }
}

// ---------------------------------------------------------------------------
// out[t] = (h[a_t] * h[b_t]) @ fc2_W + fc2_b ; one wave (64 lanes) per edge.
// fc2_W (512x7) staged in LDS; shuffle reduction over 64 lanes.
// ---------------------------------------------------------------------------
__global__ __launch_bounds__(256) void fc2_kernel(
    const float* __restrict__ h, const int* __restrict__ ei,
    const int* __restrict__ teid, const float* __restrict__ W,
    const float* __restrict__ bias, float* __restrict__ out) {
    __shared__ float Ws[HIDDEN * N_CLASS];
    __shared__ float bs[N_CLASS];
    for (int i = threadIdx.x; i < HIDDEN * N_CLASS; i += blockDim.x) Ws[i] = W[i];
    if (threadIdx.x < N_CLASS) bs[threadIdx.x] = bias[threadIdx.x];
    __syncthreads();

    int wave = threadIdx.x >> 6;
    int lane = threadIdx.x & 63;
    int t = blockIdx.x * 4 + wave;
    if (t >= N_TRAIN) return;

    int e = teid[t];
    int a = ei[e];
    int b = ei[N_EDGES + e];
    const float* xa = h + (size_t)a * HIDDEN;
    const float* xb = h + (size_t)b * HIDDEN;

    float acc[N_CLASS];
#pragma unroll
    for (int c = 0; c < N_CLASS; c++) acc[c] = 0.f;

    int j0 = lane * 8;
    float4 a0 = *(const float4*)&xa[j0];
    float4 a1 = *(const float4*)&xa[j0 + 4];
    float4 b0 = *(const float4*)&xb[j0];
    float4 b1 = *(const float4*)&xb[j0 + 4];
    float p[8] = {a0.x * b0.x, a0.y * b0.y, a0.z * b0.z, a0.w * b0.w,
                  a1.x * b1.x, a1.y * b1.y, a1.z * b1.z, a1.w * b1.w};
#pragma unroll
    for (int jj = 0; jj < 8; jj++) {
        const float* wrow = &Ws[(j0 + jj) * N_CLASS];
#pragma unroll
        for (int c = 0; c < N_CLASS; c++) acc[c] = fmaf(p[jj], wrow[c], acc[c]);
    }
#pragma unroll
    for (int c = 0; c < N_CLASS; c++) {
        float v = acc[c];
        for (int off = 32; off > 0; off >>= 1) v += __shfl_down(v, off, 64);
        if (lane == 0) out[(size_t)t * N_CLASS + c] = v + bs[c];
    }
}

// ---------------------------------------------------------------------------
extern "C" void kernel_launch(void* const* d_in, const int* in_sizes, int n_in,
                              void* d_out, int out_size, void* d_ws, size_t ws_size,
                              hipStream_t stream) {
    const float* x      = (const float*)d_in[0];
    const int*   ei     = (const int*)d_in[1];
    const int*   teid   = (const int*)d_in[2];
    const float* W1     = (const float*)d_in[3];
    const float* b1     = (const float*)d_in[4];
    const float* W2     = (const float*)d_in[5];
    const float* b2     = (const float*)d_in[6];
    const float* W3     = (const float*)d_in[7];
    const float* b3     = (const float*)d_in[8];
    const float* bn1_g  = (const float*)d_in[9];
    const float* bn1_b  = (const float*)d_in[10];
    const float* bn1_m  = (const float*)d_in[11];
    const float* bn1_v  = (const float*)d_in[12];
    const float* eps1   = (const float*)d_in[13];
    const float* W4     = (const float*)d_in[14];
    const float* b4     = (const float*)d_in[15];
    const float* bn2_g  = (const float*)d_in[16];
    const float* bn2_b  = (const float*)d_in[17];
    const float* bn2_m  = (const float*)d_in[18];
    const float* bn2_v  = (const float*)d_in[19];
    const float* eps2   = (const float*)d_in[20];
    const float* lin1_W = (const float*)d_in[21];
    const float* lin1_b = (const float*)d_in[22];
    const float* lin2_W = (const float*)d_in[23];
    const float* lin2_b = (const float*)d_in[24];
    const float* fc2_W  = (const float*)d_in[25];
    const float* fc2_b  = (const float*)d_in[26];

    // workspace layout: two ping-pong h buffers (N_NODES x HIDDEN floats each)
    const size_t HBUF = (size_t)N_NODES * HIDDEN;  // 25.6M floats
    float* B0 = (float*)d_ws;
    float* B1 = B0 + HBUF;
    float* h0 = B1;  // h0 (N_NODES x IN_F) aliases B1 (dead until gemm2 output)

    dim3 gemm_grid((N_NODES + BM - 1) / BM, HIDDEN / BN);

    // --- layer 0: h0 = (1+eps1)*x + segment_sum(x[src] -> dst) ---
    int n4a = N_NODES * IN_F / 4;
    scale_init_kernel<<<(n4a + 255) / 256, 256, 0, stream>>>(x, eps1, h0, n4a);
    int tot1 = N_EDGES * IN_F;
    edge_agg_kernel<<<(tot1 + 255) / 256, 256, 0, stream>>>(x, ei, h0, 6);

    // h1 = relu(h0 @ W1 + b1) -> B0
    gemm_kernel<<<gemm_grid, 256, 0, stream>>>(h0, W1, b1, B0, N_NODES, IN_F, 1,
                                               nullptr, nullptr, nullptr, nullptr);
    // h2 = relu(h1 @ W2 + b2) -> B1
    gemm_kernel<<<gemm_grid, 256, 0, stream>>>(B0, W2, b2, B1, N_NODES, HIDDEN, 1,
                                               nullptr, nullptr, nullptr, nullptr);
    // h3 = bn1(relu(h2 @ W3 + b3)) -> B0
    gemm_kernel<<<gemm_grid, 256, 0, stream>>>(B1, W3, b3, B0, N_NODES, HIDDEN, 2,
                                               bn1_g, bn1_b, bn1_m, bn1_v);

    // --- layer 1 agg: h4 = (1+eps2)*h3 + segment_sum(h3[src] -> dst) -> B1 ---
    int n4b = (int)(HBUF / 4);
    scale_init_kernel<<<(n4b + 255) / 256, 256, 0, stream>>>(B0, eps2, B1, n4b);
    int tot2 = N_EDGES * HIDDEN;
    edge_agg_kernel<<<(tot2 + 255) / 256, 256, 0, stream>>>(B0, ei, B1, 9);

    // h5 = bn2(relu(h4 @ W4 + b4)) -> B0
    gemm_kernel<<<gemm_grid, 256, 0, stream>>>(B1, W4, b4, B0, N_NODES, HIDDEN, 2,
                                               bn2_g, bn2_b, bn2_m, bn2_v);
    // h6 = relu(h5 @ lin1_W + lin1_b) -> B1
    gemm_kernel<<<gemm_grid, 256, 0, stream>>>(B0, lin1_W, lin1_b, B1, N_NODES, HIDDEN, 1,
                                               nullptr, nullptr, nullptr, nullptr);
    // h7 = h6 @ lin2_W + lin2_b -> B0
    gemm_kernel<<<gemm_grid, 256, 0, stream>>>(B1, lin2_W, lin2_b, B0, N_NODES, HIDDEN, 0,
                                               nullptr, nullptr, nullptr, nullptr);

    // head: out = (h7[a]*h7[b]) @ fc2_W + fc2_b
    fc2_kernel<<<(N_TRAIN + 3) / 4, 256, 0, stream>>>(B0, ei, teid, fc2_W, fc2_b,
                                                      (float*)d_out);
}

// Round 3
// 1243.299 us; speedup vs baseline: 1.7697x; 1.7697x over previous
//
#include <hip/hip_runtime.h>

#define N_NODES 50000
#define MPAD    50048           // N_NODES rounded up to 128
#define IN_F    64
#define HIDDEN  512
#define N_EDGES 160000
#define N_TRAIN 80000
#define N_CLASS 7
#define BN_EPS  1e-5f

typedef short  bf16x8 __attribute__((ext_vector_type(8)));
typedef float  f32x4  __attribute__((ext_vector_type(4)));
typedef unsigned short ushort_t;

// ---- bf16 helpers (manual RNE; values are finite) -------------------------
__device__ __forceinline__ ushort_t f2b(float v) {
    union { float f; unsigned int u; } c; c.f = v;
    unsigned int x = c.u;
    unsigned int r = (x + 0x7FFFu + ((x >> 16) & 1u)) >> 16;
    return (ushort_t)r;
}
__device__ __forceinline__ float b2f(ushort_t b) {
    union { unsigned int u; float f; } c; c.u = ((unsigned int)b) << 16;
    return c.f;
}

// ---- async global->LDS, 16B per lane (dst = wave-uniform base + lane*16) --
__device__ __forceinline__ void async_copy16(const void* g, void* l) {
    __builtin_amdgcn_global_load_lds(
        (const __attribute__((address_space(1))) void*)g,
        (__attribute__((address_space(3))) void*)l, 16, 0, 0);
}

// ---------------------------------------------------------------------------
// out[i] = (1 + *epsp) * in[i]   (float4; n4 = n/4)
// ---------------------------------------------------------------------------
__global__ void scale_init_kernel(const float* __restrict__ in,
                                  const float* __restrict__ epsp,
                                  float* __restrict__ out, int n4) {
    int i = blockIdx.x * blockDim.x + threadIdx.x;
    if (i >= n4) return;
    float s = 1.0f + *epsp;
    float4 v = ((const float4*)in)[i];
    float4 o;
    o.x = s * v.x; o.y = s * v.y; o.z = s * v.z; o.w = s * v.w;
    ((float4*)out)[i] = o;
}

// ---------------------------------------------------------------------------
// agg[dst][f] += h[src][f] over all edges. One thread per (edge, feature).
// ---------------------------------------------------------------------------
__global__ void edge_agg_kernel(const float* __restrict__ h,
                                const int* __restrict__ ei,
                                float* __restrict__ agg, int logF) {
    int gid = blockIdx.x * blockDim.x + threadIdx.x;
    int F = 1 << logF;
    int total = N_EDGES << logF;
    if (gid >= total) return;
    int e = gid >> logF;
    int f = gid & (F - 1);
    int src = ei[e];
    int dst = ei[N_EDGES + e];
    atomicAdd(&agg[dst * F + f], h[src * F + f]);
}

// ---------------------------------------------------------------------------
// fp32 [n4*4] -> split bf16 planes hi/lo (ushort4 stores)
// ---------------------------------------------------------------------------
__global__ void split_kernel(const float* __restrict__ in,
                             ushort_t* __restrict__ hi,
                             ushort_t* __restrict__ lo, int n4) {
    int i = blockIdx.x * blockDim.x + threadIdx.x;
    if (i >= n4) return;
    float4 v = ((const float4*)in)[i];
    float vv[4] = {v.x, v.y, v.z, v.w};
    ushort_t h[4], l[4];
#pragma unroll
    for (int j = 0; j < 4; j++) {
        h[j] = f2b(vv[j]);
        l[j] = f2b(vv[j] - b2f(h[j]));
    }
    ((ushort4*)hi)[i] = make_ushort4(h[0], h[1], h[2], h[3]);
    ((ushort4*)lo)[i] = make_ushort4(l[0], l[1], l[2], l[3]);
}

// ---------------------------------------------------------------------------
// W[K][512] fp32 -> Wt_hi[512][K], Wt_lo[512][K] bf16 (transpose + split)
// block 256 = 32x8, tile 32x32. grid (512/32, K/32)
// ---------------------------------------------------------------------------
__global__ void wtrans_kernel(const float* __restrict__ W,
                              ushort_t* __restrict__ Whi,
                              ushort_t* __restrict__ Wlo, int K) {
    __shared__ float t[32][33];
    int tx = threadIdx.x & 31, ty = threadIdx.x >> 5;   // ty 0..7
    int nb = blockIdx.x * 32, kb = blockIdx.y * 32;
#pragma unroll
    for (int i = 0; i < 4; i++) {
        int k = kb + ty + i * 8;
        t[ty + i * 8][tx] = W[(size_t)k * HIDDEN + nb + tx];
    }
    __syncthreads();
#pragma unroll
    for (int i = 0; i < 4; i++) {
        int n = nb + ty + i * 8;
        int k = kb + tx;
        float v = t[tx][ty + i * 8];
        ushort_t hb = f2b(v);
        ushort_t lb = f2b(v - b2f(hb));
        Whi[(size_t)n * K + k] = hb;
        Wlo[(size_t)n * K + k] = lb;
    }
}

// ---------------------------------------------------------------------------
// Split-bf16 MFMA GEMM: C = epilogue(A @ B + bias), N = 512 fixed.
// A planes [MPAD][K] bf16 (hi/lo), B planes [512][K] bf16 (transposed weights).
// 128x128 tile, BK=32, 256 threads (4 waves, 2x2), 16x16x32 MFMA,
// 3-term split accumulate (hh, hl, lh) into fp32.
// Output: fp32 (Cf) or split planes (Chi/Clo). mode 0 none, 1 relu, 2 relu+bn.
// ---------------------------------------------------------------------------
__global__ __launch_bounds__(256) void gemm_split_kernel(
    const ushort_t* __restrict__ Ahi, const ushort_t* __restrict__ Alo,
    const ushort_t* __restrict__ Bhi, const ushort_t* __restrict__ Blo,
    const float* __restrict__ bias,
    float* __restrict__ Cf, ushort_t* __restrict__ Chi, ushort_t* __restrict__ Clo,
    int K, int mode,
    const float* __restrict__ bn_g, const float* __restrict__ bn_b,
    const float* __restrict__ bn_m, const float* __restrict__ bn_v) {
    __shared__ ushort_t As_h[128 * 32];
    __shared__ ushort_t As_l[128 * 32];
    __shared__ ushort_t Bs_h[128 * 32];
    __shared__ ushort_t Bs_l[128 * 32];

    const int tid  = threadIdx.x;
    const int wave = tid >> 6, lane = tid & 63;
    const int wm = wave >> 1, wn = wave & 1;
    const int quad = lane >> 4, r = lane & 15;
    const int m0 = blockIdx.x * 128, n0 = blockIdx.y * 128;

    const f32x4 vzero = {0.f, 0.f, 0.f, 0.f};
    f32x4 acc[4][4];
#pragma unroll
    for (int i = 0; i < 4; i++)
#pragma unroll
        for (int j = 0; j < 4; j++) acc[i][j] = vzero;

    // staging geometry: per wave, per plane: 2 instrs x (16 rows x 64 B)
    const int srow = (lane >> 2);          // 0..15 row within 16-row chunk
    const int scol = (lane & 3) * 8;       // element offset within row (8 bf16 = 16 B)

    for (int k0 = 0; k0 < K; k0 += 32) {
        __syncthreads();
#pragma unroll
        for (int t = 0; t < 2; t++) {
            int rr = wave * 32 + t * 16 + srow;          // 0..127
            int lbase = (wave * 32 + t * 16) * 32;       // ushort index of chunk base
            size_t ga = (size_t)(m0 + rr) * K + k0 + scol;
            size_t gb = (size_t)(n0 + rr) * K + k0 + scol;
            async_copy16(Ahi + ga, &As_h[lbase]);
            async_copy16(Alo + ga, &As_l[lbase]);
            async_copy16(Bhi + gb, &Bs_h[lbase]);
            async_copy16(Blo + gb, &Bs_l[lbase]);
        }
        __syncthreads();

        bf16x8 ah[4], al[4], bh[4], bl[4];
#pragma unroll
        for (int i = 0; i < 4; i++) {
            int aofs = (wm * 64 + i * 16 + r) * 32 + quad * 8;
            int bofs = (wn * 64 + i * 16 + r) * 32 + quad * 8;
            ah[i] = *(const bf16x8*)&As_h[aofs];
            al[i] = *(const bf16x8*)&As_l[aofs];
            bh[i] = *(const bf16x8*)&Bs_h[bofs];
            bl[i] = *(const bf16x8*)&Bs_l[bofs];
        }
#pragma unroll
        for (int i = 0; i < 4; i++)
#pragma unroll
            for (int j = 0; j < 4; j++) {
                acc[i][j] = __builtin_amdgcn_mfma_f32_16x16x32_bf16(ah[i], bh[j], acc[i][j], 0, 0, 0);
                acc[i][j] = __builtin_amdgcn_mfma_f32_16x16x32_bf16(ah[i], bl[j], acc[i][j], 0, 0, 0);
                acc[i][j] = __builtin_amdgcn_mfma_f32_16x16x32_bf16(al[i], bh[j], acc[i][j], 0, 0, 0);
            }
    }

    // ---- epilogue: per-column params for the 4 n-tiles ----
    float bia[4], sc[4], sh[4];
#pragma unroll
    for (int j = 0; j < 4; j++) {
        int col = n0 + wn * 64 + j * 16 + r;
        bia[j] = bias[col];
        if (mode == 2) {
            float g = bn_g[col], bb = bn_b[col], mm = bn_m[col], vv = bn_v[col];
            sc[j] = g * rsqrtf(vv + BN_EPS);
            sh[j] = bb - mm * sc[j];
        } else { sc[j] = 1.f; sh[j] = 0.f; }
    }
#pragma unroll
    for (int i = 0; i < 4; i++) {
#pragma unroll
        for (int rg = 0; rg < 4; rg++) {
            int row = m0 + wm * 64 + i * 16 + quad * 4 + rg;
            if (row >= N_NODES) continue;
#pragma unroll
            for (int j = 0; j < 4; j++) {
                int col = n0 + wn * 64 + j * 16 + r;
                float v = acc[i][j][rg] + bia[j];
                if (mode >= 1) v = fmaxf(v, 0.f);
                if (mode == 2) v = v * sc[j] + sh[j];
                size_t idx = (size_t)row * HIDDEN + col;
                if (Cf) {
                    Cf[idx] = v;
                } else {
                    ushort_t hb = f2b(v);
                    ushort_t lb = f2b(v - b2f(hb));
                    Chi[idx] = hb;
                    Clo[idx] = lb;
                }
            }
        }
    }
}

// ---------------------------------------------------------------------------
// out[t] = (h[a_t] * h[b_t]) @ fc2_W + fc2_b ; one wave per train edge.
// ---------------------------------------------------------------------------
__global__ __launch_bounds__(256) void fc2_kernel(
    const float* __restrict__ h, const int* __restrict__ ei,
    const int* __restrict__ teid, const float* __restrict__ W,
    const float* __restrict__ bias, float* __restrict__ out) {
    __shared__ float Ws[HIDDEN * N_CLASS];
    __shared__ float bs[N_CLASS];
    for (int i = threadIdx.x; i < HIDDEN * N_CLASS; i += blockDim.x) Ws[i] = W[i];
    if (threadIdx.x < N_CLASS) bs[threadIdx.x] = bias[threadIdx.x];
    __syncthreads();

    int wave = threadIdx.x >> 6;
    int lane = threadIdx.x & 63;
    int t = blockIdx.x * 4 + wave;
    if (t >= N_TRAIN) return;

    int e = teid[t];
    int a = ei[e];
    int b = ei[N_EDGES + e];
    const float* xa = h + (size_t)a * HIDDEN;
    const float* xb = h + (size_t)b * HIDDEN;

    float acc[N_CLASS];
#pragma unroll
    for (int c = 0; c < N_CLASS; c++) acc[c] = 0.f;

    int j0 = lane * 8;
    float4 a0 = *(const float4*)&xa[j0];
    float4 a1 = *(const float4*)&xa[j0 + 4];
    float4 b0 = *(const float4*)&xb[j0];
    float4 b1 = *(const float4*)&xb[j0 + 4];
    float p[8] = {a0.x * b0.x, a0.y * b0.y, a0.z * b0.z, a0.w * b0.w,
                  a1.x * b1.x, a1.y * b1.y, a1.z * b1.z, a1.w * b1.w};
#pragma unroll
    for (int jj = 0; jj < 8; jj++) {
        const float* wrow = &Ws[(j0 + jj) * N_CLASS];
#pragma unroll
        for (int c = 0; c < N_CLASS; c++) acc[c] = fmaf(p[jj], wrow[c], acc[c]);
    }
#pragma unroll
    for (int c = 0; c < N_CLASS; c++) {
        float v = acc[c];
        for (int off = 32; off > 0; off >>= 1) v += __shfl_down(v, off, 64);
        if (lane == 0) out[(size_t)t * N_CLASS + c] = v + bs[c];
    }
}

// ---------------------------------------------------------------------------
// Workspace (210.4 MB total):
//   R0h R0l R1h R1l : 4 bf16 planes of PLANE ushorts (ping-pong split pairs)
//   weights         : 2*WSMALL + 10*WBIG ushorts
// fp32 staging buffers ALIAS the plane pairs (one pair == PLANE floats):
//   h0 fp32 + H0 split  live at head of R1 (dead before gemm2 writes R1)
//   h3 fp32 -> R0 pair (h1 dead) ; h4 fp32 -> R1 pair (h2 dead)
//   split(h4) -> R0 (h3 dead)   ; h7 fp32 -> R1 pair (h5 dead)
// ---------------------------------------------------------------------------
extern "C" void kernel_launch(void* const* d_in, const int* in_sizes, int n_in,
                              void* d_out, int out_size, void* d_ws, size_t ws_size,
                              hipStream_t stream) {
    const float* x      = (const float*)d_in[0];
    const int*   ei     = (const int*)d_in[1];
    const int*   teid   = (const int*)d_in[2];
    const float* W1     = (const float*)d_in[3];
    const float* b1     = (const float*)d_in[4];
    const float* W2     = (const float*)d_in[5];
    const float* b2     = (const float*)d_in[6];
    const float* W3     = (const float*)d_in[7];
    const float* b3     = (const float*)d_in[8];
    const float* bn1_g  = (const float*)d_in[9];
    const float* bn1_b  = (const float*)d_in[10];
    const float* bn1_m  = (const float*)d_in[11];
    const float* bn1_v  = (const float*)d_in[12];
    const float* eps1   = (const float*)d_in[13];
    const float* W4     = (const float*)d_in[14];
    const float* b4     = (const float*)d_in[15];
    const float* bn2_g  = (const float*)d_in[16];
    const float* bn2_b  = (const float*)d_in[17];
    const float* bn2_m  = (const float*)d_in[18];
    const float* bn2_v  = (const float*)d_in[19];
    const float* eps2   = (const float*)d_in[20];
    const float* lin1_W = (const float*)d_in[21];
    const float* lin1_b = (const float*)d_in[22];
    const float* lin2_W = (const float*)d_in[23];
    const float* lin2_b = (const float*)d_in[24];
    const float* fc2_W  = (const float*)d_in[25];
    const float* fc2_b  = (const float*)d_in[26];

    const size_t PLANE   = (size_t)MPAD * HIDDEN;   // 512-wide bf16 plane (ushorts)
    const size_t PLANE64 = (size_t)MPAD * IN_F;     // 64-wide bf16 plane

    ushort_t* R0h = (ushort_t*)d_ws;
    ushort_t* R0l = R0h + PLANE;
    ushort_t* R1h = R0l + PLANE;
    ushort_t* R1l = R1h + PLANE;

    // weights after the 4 planes
    const size_t WSMALL = (size_t)HIDDEN * IN_F;    // 512*64
    const size_t WBIG   = (size_t)HIDDEN * HIDDEN;  // 512*512
    ushort_t* Wp   = R1l + PLANE;
    ushort_t* Wt1h = Wp;            ushort_t* Wt1l = Wt1h + WSMALL;
    ushort_t* Wt2h = Wt1l + WSMALL; ushort_t* Wt2l = Wt2h + WBIG;
    ushort_t* Wt3h = Wt2l + WBIG;   ushort_t* Wt3l = Wt3h + WBIG;
    ushort_t* Wt4h = Wt3l + WBIG;   ushort_t* Wt4l = Wt4h + WBIG;
    ushort_t* Wt5h = Wt4l + WBIG;   ushort_t* Wt5l = Wt5h + WBIG;
    ushort_t* Wt6h = Wt5l + WBIG;   ushort_t* Wt6l = Wt6h + WBIG;

    // fp32 aliases (each pair region == PLANE floats)
    float* F32_R0 = (float*)R0h;    // h3
    float* F32_R1 = (float*)R1h;    // h4, later h7
    // h0 fp32 + its split planes, all inside R1 (<= 25.6 MB of 102.5)
    float*    H0f = (float*)R1h;                    // MPAD*64 floats
    ushort_t* H0h = (ushort_t*)(H0f + PLANE64);
    ushort_t* H0l = H0h + PLANE64;

    // ---- weight prep: transpose + split ----
    dim3 wtgS(HIDDEN / 32, IN_F / 32);
    dim3 wtgB(HIDDEN / 32, HIDDEN / 32);
    wtrans_kernel<<<wtgS, 256, 0, stream>>>(W1, Wt1h, Wt1l, IN_F);
    wtrans_kernel<<<wtgB, 256, 0, stream>>>(W2, Wt2h, Wt2l, HIDDEN);
    wtrans_kernel<<<wtgB, 256, 0, stream>>>(W3, Wt3h, Wt3l, HIDDEN);
    wtrans_kernel<<<wtgB, 256, 0, stream>>>(W4, Wt4h, Wt4l, HIDDEN);
    wtrans_kernel<<<wtgB, 256, 0, stream>>>(lin1_W, Wt5h, Wt5l, HIDDEN);
    wtrans_kernel<<<wtgB, 256, 0, stream>>>(lin2_W, Wt6h, Wt6l, HIDDEN);

    dim3 gg(MPAD / 128, HIDDEN / 128);

    // ---- layer 0 aggregation: h0 = (1+eps1)*x + seg_sum(x) -> H0f (in R1) ----
    int n4a = N_NODES * IN_F / 4;
    scale_init_kernel<<<(n4a + 255) / 256, 256, 0, stream>>>(x, eps1, H0f, n4a);
    int tot1 = N_EDGES * IN_F;
    edge_agg_kernel<<<(tot1 + 255) / 256, 256, 0, stream>>>(x, ei, H0f, 6);
    split_kernel<<<(n4a + 255) / 256, 256, 0, stream>>>(H0f, H0h, H0l, n4a);

    // h1 = relu(h0 @ W1 + b1) -> R0 (split)
    gemm_split_kernel<<<gg, 256, 0, stream>>>(H0h, H0l, Wt1h, Wt1l, b1,
        nullptr, R0h, R0l, IN_F, 1, nullptr, nullptr, nullptr, nullptr);
    // h2 = relu(h1 @ W2 + b2) -> R1 (split; overwrites dead h0/H0)
    gemm_split_kernel<<<gg, 256, 0, stream>>>(R0h, R0l, Wt2h, Wt2l, b2,
        nullptr, R1h, R1l, HIDDEN, 1, nullptr, nullptr, nullptr, nullptr);
    // h3 = bn1(relu(h2 @ W3 + b3)) -> F32_R0 (h1 dead)
    gemm_split_kernel<<<gg, 256, 0, stream>>>(R1h, R1l, Wt3h, Wt3l, b3,
        F32_R0, nullptr, nullptr, HIDDEN, 2, bn1_g, bn1_b, bn1_m, bn1_v);

    // ---- layer 1 aggregation: h4 = (1+eps2)*h3 + seg_sum(h3) -> F32_R1 (h2 dead)
    int n4b = N_NODES * HIDDEN / 4;
    scale_init_kernel<<<(n4b + 255) / 256, 256, 0, stream>>>(F32_R0, eps2, F32_R1, n4b);
    int tot2 = N_EDGES * HIDDEN;
    edge_agg_kernel<<<(tot2 + 255) / 256, 256, 0, stream>>>(F32_R0, ei, F32_R1, 9);
    // split h4 -> R0 (h3 fp32 dead)
    split_kernel<<<(n4b + 255) / 256, 256, 0, stream>>>(F32_R1, R0h, R0l, n4b);

    // h5 = bn2(relu(h4 @ W4 + b4)) -> R1 (split; h4 fp32 dead)
    gemm_split_kernel<<<gg, 256, 0, stream>>>(R0h, R0l, Wt4h, Wt4l, b4,
        nullptr, R1h, R1l, HIDDEN, 2, bn2_g, bn2_b, bn2_m, bn2_v);
    // h6 = relu(h5 @ lin1_W + lin1_b) -> R0 (split)
    gemm_split_kernel<<<gg, 256, 0, stream>>>(R1h, R1l, Wt5h, Wt5l, lin1_b,
        nullptr, R0h, R0l, HIDDEN, 1, nullptr, nullptr, nullptr, nullptr);
    // h7 = h6 @ lin2_W + lin2_b -> F32_R1 (h5 dead)
    gemm_split_kernel<<<gg, 256, 0, stream>>>(R0h, R0l, Wt6h, Wt6l, lin2_b,
        F32_R1, nullptr, nullptr, HIDDEN, 0, nullptr, nullptr, nullptr, nullptr);

    // head
    fc2_kernel<<<(N_TRAIN + 3) / 4, 256, 0, stream>>>(F32_R1, ei, teid, fc2_W, fc2_b,
                                                      (float*)d_out);
}

// Round 4
// 1084.167 us; speedup vs baseline: 2.0295x; 1.1468x over previous
//
#include <hip/hip_runtime.h>

#define N_NODES 50000
#define MPAD    50048           // N_NODES rounded up to 128
#define IN_F    64
#define HIDDEN  512
#define N_EDGES 160000
#define N_TRAIN 80000
#define N_CLASS 7
#define BN_EPS  1e-5f

typedef short  bf16x8 __attribute__((ext_vector_type(8)));
typedef float  f32x4  __attribute__((ext_vector_type(4)));
typedef unsigned short ushort_t;

// ---- bf16 helpers (manual RNE; values are finite) -------------------------
__device__ __forceinline__ ushort_t f2b(float v) {
    union { float f; unsigned int u; } c; c.f = v;
    unsigned int x = c.u;
    unsigned int r = (x + 0x7FFFu + ((x >> 16) & 1u)) >> 16;
    return (ushort_t)r;
}
__device__ __forceinline__ float b2f(ushort_t b) {
    union { unsigned int u; float f; } c; c.u = ((unsigned int)b) << 16;
    return c.f;
}

// ---- async global->LDS, 16B per lane (dst = wave-uniform base + lane*16) --
__device__ __forceinline__ void async_copy16(const void* g, void* l) {
    __builtin_amdgcn_global_load_lds(
        (const __attribute__((address_space(1))) void*)g,
        (__attribute__((address_space(3))) void*)l, 16, 0, 0);
}

// ===========================================================================
// CSR build: zero -> histogram(dst) -> exclusive scan -> scatter src ids
// ===========================================================================
__global__ void zero_kernel(int* __restrict__ p, int n) {
    int i = blockIdx.x * blockDim.x + threadIdx.x;
    if (i < n) p[i] = 0;
}

__global__ void hist_kernel(const int* __restrict__ ei, int* __restrict__ deg) {
    int e = blockIdx.x * blockDim.x + threadIdx.x;
    if (e >= N_EDGES) return;
    atomicAdd(&deg[ei[N_EDGES + e]], 1);
}

// single block, 1024 threads; rowptr[0]=0, rowptr[i+1]=incl_scan(deg)[i]
__global__ __launch_bounds__(1024) void scan_kernel(const int* __restrict__ deg,
                                                    int* __restrict__ rowptr) {
    __shared__ int buf[1024];
    __shared__ int carry_s;
    int tid = threadIdx.x;
    if (tid == 0) { carry_s = 0; rowptr[0] = 0; }
    __syncthreads();
    for (int base = 0; base < N_NODES; base += 1024) {
        int i = base + tid;
        buf[tid] = (i < N_NODES) ? deg[i] : 0;
        __syncthreads();
        for (int off = 1; off < 1024; off <<= 1) {
            int t = (tid >= off) ? buf[tid - off] : 0;
            __syncthreads();
            buf[tid] += t;
            __syncthreads();
        }
        if (i < N_NODES) rowptr[i + 1] = buf[tid] + carry_s;
        __syncthreads();
        if (tid == 0) carry_s += buf[1023];
        __syncthreads();
    }
}

__global__ void cursor_init_kernel(const int* __restrict__ rowptr,
                                   int* __restrict__ cursor) {
    int i = blockIdx.x * blockDim.x + threadIdx.x;
    if (i < N_NODES) cursor[i] = rowptr[i];
}

__global__ void scatter_kernel(const int* __restrict__ ei,
                               int* __restrict__ cursor, int* __restrict__ adj) {
    int e = blockIdx.x * blockDim.x + threadIdx.x;
    if (e >= N_EDGES) return;
    int src = ei[e], dst = ei[N_EDGES + e];
    int pos = atomicAdd(&cursor[dst], 1);
    adj[pos] = src;
}

// ===========================================================================
// Gather aggregation (CSR), fused scale + split-bf16 output.
// out[n] = (1+eps)*h[n] + sum_{k in row n} h[adj[k]]
// ===========================================================================
// F = 64: one wave per node, lane = feature.
__global__ __launch_bounds__(256) void gather64_kernel(
    const float* __restrict__ x, const int* __restrict__ rowptr,
    const int* __restrict__ adj, const float* __restrict__ epsp,
    ushort_t* __restrict__ hi, ushort_t* __restrict__ lo) {
    int wave = threadIdx.x >> 6, lane = threadIdx.x & 63;
    int n = blockIdx.x * 4 + wave;
    if (n >= N_NODES) return;
    float s = 1.0f + *epsp;
    float sum = s * x[(size_t)n * IN_F + lane];
    int beg = rowptr[n], end = rowptr[n + 1];
    for (int k = beg; k < end; k++) {
        sum += x[(size_t)adj[k] * IN_F + lane];
    }
    ushort_t hb = f2b(sum);
    ushort_t lb = f2b(sum - b2f(hb));
    hi[(size_t)n * IN_F + lane] = hb;
    lo[(size_t)n * IN_F + lane] = lb;
}

// F = 512: one wave per node, lane covers f = lane*4 (+0..3) and 256+lane*4.
__global__ __launch_bounds__(256) void gather512_kernel(
    const float* __restrict__ h, const int* __restrict__ rowptr,
    const int* __restrict__ adj, const float* __restrict__ epsp,
    ushort_t* __restrict__ hi, ushort_t* __restrict__ lo) {
    int wave = threadIdx.x >> 6, lane = threadIdx.x & 63;
    int n = blockIdx.x * 4 + wave;
    if (n >= N_NODES) return;
    float s = 1.0f + *epsp;
    const float* hn = h + (size_t)n * HIDDEN;
    const int f0 = lane * 4, f1 = 256 + lane * 4;
    float4 a0 = *(const float4*)&hn[f0];
    float4 a1 = *(const float4*)&hn[f1];
    float sum0[4] = {s * a0.x, s * a0.y, s * a0.z, s * a0.w};
    float sum1[4] = {s * a1.x, s * a1.y, s * a1.z, s * a1.w};
    int beg = rowptr[n], end = rowptr[n + 1];
    for (int k = beg; k < end; k++) {
        const float* hs = h + (size_t)adj[k] * HIDDEN;
        float4 b0 = *(const float4*)&hs[f0];
        float4 b1 = *(const float4*)&hs[f1];
        sum0[0] += b0.x; sum0[1] += b0.y; sum0[2] += b0.z; sum0[3] += b0.w;
        sum1[0] += b1.x; sum1[1] += b1.y; sum1[2] += b1.z; sum1[3] += b1.w;
    }
    ushort_t h4[4], l4[4];
#pragma unroll
    for (int j = 0; j < 4; j++) {
        h4[j] = f2b(sum0[j]);
        l4[j] = f2b(sum0[j] - b2f(h4[j]));
    }
    *(ushort4*)&hi[(size_t)n * HIDDEN + f0] = make_ushort4(h4[0], h4[1], h4[2], h4[3]);
    *(ushort4*)&lo[(size_t)n * HIDDEN + f0] = make_ushort4(l4[0], l4[1], l4[2], l4[3]);
#pragma unroll
    for (int j = 0; j < 4; j++) {
        h4[j] = f2b(sum1[j]);
        l4[j] = f2b(sum1[j] - b2f(h4[j]));
    }
    *(ushort4*)&hi[(size_t)n * HIDDEN + f1] = make_ushort4(h4[0], h4[1], h4[2], h4[3]);
    *(ushort4*)&lo[(size_t)n * HIDDEN + f1] = make_ushort4(l4[0], l4[1], l4[2], l4[3]);
}

// ---------------------------------------------------------------------------
// W[K][512] fp32 -> Wt_hi[512][K], Wt_lo[512][K] bf16 (transpose + split)
// ---------------------------------------------------------------------------
__global__ void wtrans_kernel(const float* __restrict__ W,
                              ushort_t* __restrict__ Whi,
                              ushort_t* __restrict__ Wlo, int K) {
    __shared__ float t[32][33];
    int tx = threadIdx.x & 31, ty = threadIdx.x >> 5;   // ty 0..7
    int nb = blockIdx.x * 32, kb = blockIdx.y * 32;
#pragma unroll
    for (int i = 0; i < 4; i++) {
        int k = kb + ty + i * 8;
        t[ty + i * 8][tx] = W[(size_t)k * HIDDEN + nb + tx];
    }
    __syncthreads();
#pragma unroll
    for (int i = 0; i < 4; i++) {
        int n = nb + ty + i * 8;
        int k = kb + tx;
        float v = t[tx][ty + i * 8];
        ushort_t hb = f2b(v);
        ushort_t lb = f2b(v - b2f(hb));
        Whi[(size_t)n * K + k] = hb;
        Wlo[(size_t)n * K + k] = lb;
    }
}

// ---------------------------------------------------------------------------
// Split-bf16 MFMA GEMM: C = epilogue(A @ B + bias), N = 512 fixed.
// 128x128 tile, BK=32, 256 threads (4 waves 2x2), 16x16x32 MFMA, 3-term split.
// mode 0 none, 1 relu, 2 relu+bn. Output fp32 (Cf) or split planes (Chi/Clo).
// ---------------------------------------------------------------------------
__global__ __launch_bounds__(256) void gemm_split_kernel(
    const ushort_t* __restrict__ Ahi, const ushort_t* __restrict__ Alo,
    const ushort_t* __restrict__ Bhi, const ushort_t* __restrict__ Blo,
    const float* __restrict__ bias,
    float* __restrict__ Cf, ushort_t* __restrict__ Chi, ushort_t* __restrict__ Clo,
    int K, int mode,
    const float* __restrict__ bn_g, const float* __restrict__ bn_b,
    const float* __restrict__ bn_m, const float* __restrict__ bn_v) {
    __shared__ ushort_t As_h[128 * 32];
    __shared__ ushort_t As_l[128 * 32];
    __shared__ ushort_t Bs_h[128 * 32];
    __shared__ ushort_t Bs_l[128 * 32];

    const int tid  = threadIdx.x;
    const int wave = tid >> 6, lane = tid & 63;
    const int wm = wave >> 1, wn = wave & 1;
    const int quad = lane >> 4, r = lane & 15;
    const int m0 = blockIdx.x * 128, n0 = blockIdx.y * 128;

    const f32x4 vzero = {0.f, 0.f, 0.f, 0.f};
    f32x4 acc[4][4];
#pragma unroll
    for (int i = 0; i < 4; i++)
#pragma unroll
        for (int j = 0; j < 4; j++) acc[i][j] = vzero;

    const int srow = (lane >> 2);          // 0..15
    const int scol = (lane & 3) * 8;       // 8 bf16 = 16 B

    for (int k0 = 0; k0 < K; k0 += 32) {
        __syncthreads();
#pragma unroll
        for (int t = 0; t < 2; t++) {
            int rr = wave * 32 + t * 16 + srow;
            int lbase = (wave * 32 + t * 16) * 32;
            size_t ga = (size_t)(m0 + rr) * K + k0 + scol;
            size_t gb = (size_t)(n0 + rr) * K + k0 + scol;
            async_copy16(Ahi + ga, &As_h[lbase]);
            async_copy16(Alo + ga, &As_l[lbase]);
            async_copy16(Bhi + gb, &Bs_h[lbase]);
            async_copy16(Blo + gb, &Bs_l[lbase]);
        }
        __syncthreads();

        bf16x8 ah[4], al[4], bh[4], bl[4];
#pragma unroll
        for (int i = 0; i < 4; i++) {
            int aofs = (wm * 64 + i * 16 + r) * 32 + quad * 8;
            int bofs = (wn * 64 + i * 16 + r) * 32 + quad * 8;
            ah[i] = *(const bf16x8*)&As_h[aofs];
            al[i] = *(const bf16x8*)&As_l[aofs];
            bh[i] = *(const bf16x8*)&Bs_h[bofs];
            bl[i] = *(const bf16x8*)&Bs_l[bofs];
        }
#pragma unroll
        for (int i = 0; i < 4; i++)
#pragma unroll
            for (int j = 0; j < 4; j++) {
                acc[i][j] = __builtin_amdgcn_mfma_f32_16x16x32_bf16(ah[i], bh[j], acc[i][j], 0, 0, 0);
                acc[i][j] = __builtin_amdgcn_mfma_f32_16x16x32_bf16(ah[i], bl[j], acc[i][j], 0, 0, 0);
                acc[i][j] = __builtin_amdgcn_mfma_f32_16x16x32_bf16(al[i], bh[j], acc[i][j], 0, 0, 0);
            }
    }

    float bia[4], sc[4], sh[4];
#pragma unroll
    for (int j = 0; j < 4; j++) {
        int col = n0 + wn * 64 + j * 16 + r;
        bia[j] = bias[col];
        if (mode == 2) {
            float g = bn_g[col], bb = bn_b[col], mm = bn_m[col], vv = bn_v[col];
            sc[j] = g * rsqrtf(vv + BN_EPS);
            sh[j] = bb - mm * sc[j];
        } else { sc[j] = 1.f; sh[j] = 0.f; }
    }
#pragma unroll
    for (int i = 0; i < 4; i++) {
#pragma unroll
        for (int rg = 0; rg < 4; rg++) {
            int row = m0 + wm * 64 + i * 16 + quad * 4 + rg;
            if (row >= N_NODES) continue;
#pragma unroll
            for (int j = 0; j < 4; j++) {
                int col = n0 + wn * 64 + j * 16 + r;
                float v = acc[i][j][rg] + bia[j];
                if (mode >= 1) v = fmaxf(v, 0.f);
                if (mode == 2) v = v * sc[j] + sh[j];
                size_t idx = (size_t)row * HIDDEN + col;
                if (Cf) {
                    Cf[idx] = v;
                } else {
                    ushort_t hb = f2b(v);
                    ushort_t lb = f2b(v - b2f(hb));
                    Chi[idx] = hb;
                    Clo[idx] = lb;
                }
            }
        }
    }
}

// ---------------------------------------------------------------------------
// out[t] = (h[a_t] * h[b_t]) @ fc2_W + fc2_b ; one wave per train edge.
// ---------------------------------------------------------------------------
__global__ __launch_bounds__(256) void fc2_kernel(
    const float* __restrict__ h, const int* __restrict__ ei,
    const int* __restrict__ teid, const float* __restrict__ W,
    const float* __restrict__ bias, float* __restrict__ out) {
    __shared__ float Ws[HIDDEN * N_CLASS];
    __shared__ float bs[N_CLASS];
    for (int i = threadIdx.x; i < HIDDEN * N_CLASS; i += blockDim.x) Ws[i] = W[i];
    if (threadIdx.x < N_CLASS) bs[threadIdx.x] = bias[threadIdx.x];
    __syncthreads();

    int wave = threadIdx.x >> 6;
    int lane = threadIdx.x & 63;
    int t = blockIdx.x * 4 + wave;
    if (t >= N_TRAIN) return;

    int e = teid[t];
    int a = ei[e];
    int b = ei[N_EDGES + e];
    const float* xa = h + (size_t)a * HIDDEN;
    const float* xb = h + (size_t)b * HIDDEN;

    float acc[N_CLASS];
#pragma unroll
    for (int c = 0; c < N_CLASS; c++) acc[c] = 0.f;

    int j0 = lane * 8;
    float4 a0 = *(const float4*)&xa[j0];
    float4 a1 = *(const float4*)&xa[j0 + 4];
    float4 b0 = *(const float4*)&xb[j0];
    float4 b1 = *(const float4*)&xb[j0 + 4];
    float p[8] = {a0.x * b0.x, a0.y * b0.y, a0.z * b0.z, a0.w * b0.w,
                  a1.x * b1.x, a1.y * b1.y, a1.z * b1.z, a1.w * b1.w};
#pragma unroll
    for (int jj = 0; jj < 8; jj++) {
        const float* wrow = &Ws[(j0 + jj) * N_CLASS];
#pragma unroll
        for (int c = 0; c < N_CLASS; c++) acc[c] = fmaf(p[jj], wrow[c], acc[c]);
    }
#pragma unroll
    for (int c = 0; c < N_CLASS; c++) {
        float v = acc[c];
        for (int off = 32; off > 0; off >>= 1) v += __shfl_down(v, off, 64);
        if (lane == 0) out[(size_t)t * N_CLASS + c] = v + bs[c];
    }
}

// ---------------------------------------------------------------------------
// Workspace (~211.4 MB):
//   R0h R0l R1h R1l (4 bf16 planes) | weights | CSR {deg/cursor, rowptr, adj}
// Liveness chain:
//   gather64 -> H0 split (head of R1)          [x input]
//   gemm1: H0 -> h1 split (R0)
//   gemm2: R0 -> h2 split (R1, kills H0)
//   gemm3: R1 -> h3 fp32  (F32_R0, kills h1)
//   gather512: F32_R0 -> h4 split (R1, kills h2)
//   gemm4: R1 -> h5 split (R0, kills h3)
//   gemm5: R0 -> h6 split (R1, kills h4)
//   gemm6: R1 -> h7 fp32  (F32_R0, kills h5)
//   fc2:   F32_R0 -> out
// ---------------------------------------------------------------------------
extern "C" void kernel_launch(void* const* d_in, const int* in_sizes, int n_in,
                              void* d_out, int out_size, void* d_ws, size_t ws_size,
                              hipStream_t stream) {
    const float* x      = (const float*)d_in[0];
    const int*   ei     = (const int*)d_in[1];
    const int*   teid   = (const int*)d_in[2];
    const float* W1     = (const float*)d_in[3];
    const float* b1     = (const float*)d_in[4];
    const float* W2     = (const float*)d_in[5];
    const float* b2     = (const float*)d_in[6];
    const float* W3     = (const float*)d_in[7];
    const float* b3     = (const float*)d_in[8];
    const float* bn1_g  = (const float*)d_in[9];
    const float* bn1_b  = (const float*)d_in[10];
    const float* bn1_m  = (const float*)d_in[11];
    const float* bn1_v  = (const float*)d_in[12];
    const float* eps1   = (const float*)d_in[13];
    const float* W4     = (const float*)d_in[14];
    const float* b4     = (const float*)d_in[15];
    const float* bn2_g  = (const float*)d_in[16];
    const float* bn2_b  = (const float*)d_in[17];
    const float* bn2_m  = (const float*)d_in[18];
    const float* bn2_v  = (const float*)d_in[19];
    const float* eps2   = (const float*)d_in[20];
    const float* lin1_W = (const float*)d_in[21];
    const float* lin1_b = (const float*)d_in[22];
    const float* lin2_W = (const float*)d_in[23];
    const float* lin2_b = (const float*)d_in[24];
    const float* fc2_W  = (const float*)d_in[25];
    const float* fc2_b  = (const float*)d_in[26];

    const size_t PLANE   = (size_t)MPAD * HIDDEN;
    const size_t PLANE64 = (size_t)MPAD * IN_F;

    ushort_t* R0h = (ushort_t*)d_ws;
    ushort_t* R0l = R0h + PLANE;
    ushort_t* R1h = R0l + PLANE;
    ushort_t* R1l = R1h + PLANE;

    const size_t WSMALL = (size_t)HIDDEN * IN_F;
    const size_t WBIG   = (size_t)HIDDEN * HIDDEN;
    ushort_t* Wp   = R1l + PLANE;
    ushort_t* Wt1h = Wp;            ushort_t* Wt1l = Wt1h + WSMALL;
    ushort_t* Wt2h = Wt1l + WSMALL; ushort_t* Wt2l = Wt2h + WBIG;
    ushort_t* Wt3h = Wt2l + WBIG;   ushort_t* Wt3l = Wt3h + WBIG;
    ushort_t* Wt4h = Wt3l + WBIG;   ushort_t* Wt4l = Wt4h + WBIG;
    ushort_t* Wt5h = Wt4l + WBIG;   ushort_t* Wt5l = Wt5h + WBIG;
    ushort_t* Wt6h = Wt5l + WBIG;   ushort_t* Wt6l = Wt6h + WBIG;

    // CSR arrays (ints) after weights
    int* deg    = (int*)(Wt6l + WBIG);   // also scatter cursor
    int* rowptr = deg + N_NODES;         // N_NODES + 1
    int* adj    = rowptr + (N_NODES + 1);

    // fp32 aliases
    float* F32_R0 = (float*)R0h;
    // H0 split planes at head of R1 region
    ushort_t* H0h = R1h;
    ushort_t* H0l = R1h + PLANE64;

    // ---- CSR build ----
    zero_kernel<<<(N_NODES + 255) / 256, 256, 0, stream>>>(deg, N_NODES);
    hist_kernel<<<(N_EDGES + 255) / 256, 256, 0, stream>>>(ei, deg);
    scan_kernel<<<1, 1024, 0, stream>>>(deg, rowptr);
    cursor_init_kernel<<<(N_NODES + 255) / 256, 256, 0, stream>>>(rowptr, deg);
    scatter_kernel<<<(N_EDGES + 255) / 256, 256, 0, stream>>>(ei, deg, adj);

    // ---- weight prep: transpose + split ----
    dim3 wtgS(HIDDEN / 32, IN_F / 32);
    dim3 wtgB(HIDDEN / 32, HIDDEN / 32);
    wtrans_kernel<<<wtgS, 256, 0, stream>>>(W1, Wt1h, Wt1l, IN_F);
    wtrans_kernel<<<wtgB, 256, 0, stream>>>(W2, Wt2h, Wt2l, HIDDEN);
    wtrans_kernel<<<wtgB, 256, 0, stream>>>(W3, Wt3h, Wt3l, HIDDEN);
    wtrans_kernel<<<wtgB, 256, 0, stream>>>(W4, Wt4h, Wt4l, HIDDEN);
    wtrans_kernel<<<wtgB, 256, 0, stream>>>(lin1_W, Wt5h, Wt5l, HIDDEN);
    wtrans_kernel<<<wtgB, 256, 0, stream>>>(lin2_W, Wt6h, Wt6l, HIDDEN);

    dim3 gg(MPAD / 128, HIDDEN / 128);
    int nwb = (N_NODES + 3) / 4;   // wave-per-node blocks (4 waves/block)

    // ---- h0 = (1+eps1)*x + gather(x) -> H0 split ----
    gather64_kernel<<<nwb, 256, 0, stream>>>(x, rowptr, adj, eps1, H0h, H0l);

    // h1 = relu(h0 @ W1 + b1) -> R0 split
    gemm_split_kernel<<<gg, 256, 0, stream>>>(H0h, H0l, Wt1h, Wt1l, b1,
        nullptr, R0h, R0l, IN_F, 1, nullptr, nullptr, nullptr, nullptr);
    // h2 = relu(h1 @ W2 + b2) -> R1 split
    gemm_split_kernel<<<gg, 256, 0, stream>>>(R0h, R0l, Wt2h, Wt2l, b2,
        nullptr, R1h, R1l, HIDDEN, 1, nullptr, nullptr, nullptr, nullptr);
    // h3 = bn1(relu(h2 @ W3 + b3)) -> F32_R0
    gemm_split_kernel<<<gg, 256, 0, stream>>>(R1h, R1l, Wt3h, Wt3l, b3,
        F32_R0, nullptr, nullptr, HIDDEN, 2, bn1_g, bn1_b, bn1_m, bn1_v);

    // ---- h4 = (1+eps2)*h3 + gather(h3) -> R1 split ----
    gather512_kernel<<<nwb, 256, 0, stream>>>(F32_R0, rowptr, adj, eps2, R1h, R1l);

    // h5 = bn2(relu(h4 @ W4 + b4)) -> R0 split
    gemm_split_kernel<<<gg, 256, 0, stream>>>(R1h, R1l, Wt4h, Wt4l, b4,
        nullptr, R0h, R0l, HIDDEN, 2, bn2_g, bn2_b, bn2_m, bn2_v);
    // h6 = relu(h5 @ lin1_W + lin1_b) -> R1 split
    gemm_split_kernel<<<gg, 256, 0, stream>>>(R0h, R0l, Wt5h, Wt5l, lin1_b,
        nullptr, R1h, R1l, HIDDEN, 1, nullptr, nullptr, nullptr, nullptr);
    // h7 = h6 @ lin2_W + lin2_b -> F32_R0
    gemm_split_kernel<<<gg, 256, 0, stream>>>(R1h, R1l, Wt6h, Wt6l, lin2_b,
        F32_R0, nullptr, nullptr, HIDDEN, 0, nullptr, nullptr, nullptr, nullptr);

    // head
    fc2_kernel<<<(N_TRAIN + 3) / 4, 256, 0, stream>>>(F32_R0, ei, teid, fc2_W, fc2_b,
                                                      (float*)d_out);
}

// Round 5
// 1045.790 us; speedup vs baseline: 2.1040x; 1.0367x over previous
//
#include <hip/hip_runtime.h>

#define N_NODES 50000
#define MPAD    50048           // N_NODES rounded up to 128
#define IN_F    64
#define HIDDEN  512
#define N_EDGES 160000
#define N_TRAIN 80000
#define N_CLASS 7
#define BN_EPS  1e-5f

#define MT      (MPAD / 128)    // 391 m-tiles
#define NT      4               // 128-col n-tiles
#define FULLGRP ((MT / 8) * 32) // 1536: full 8-mtile x 4-ntile swizzle groups

typedef short  bf16x8 __attribute__((ext_vector_type(8)));
typedef float  f32x4  __attribute__((ext_vector_type(4)));
typedef unsigned short ushort_t;

// ---- bf16 helpers (manual RNE; values are finite) -------------------------
__device__ __forceinline__ ushort_t f2b(float v) {
    union { float f; unsigned int u; } c; c.f = v;
    unsigned int x = c.u;
    unsigned int r = (x + 0x7FFFu + ((x >> 16) & 1u)) >> 16;
    return (ushort_t)r;
}
__device__ __forceinline__ float b2f(ushort_t b) {
    union { unsigned int u; float f; } c; c.u = ((unsigned int)b) << 16;
    return c.f;
}

// ---- async global->LDS, 16B per lane (dst = wave-uniform base + lane*16) --
__device__ __forceinline__ void async_copy16(const void* g, void* l) {
    __builtin_amdgcn_global_load_lds(
        (const __attribute__((address_space(1))) void*)g,
        (__attribute__((address_space(3))) void*)l, 16, 0, 0);
}

// ===========================================================================
// CSR build: zero -> histogram(dst) -> exclusive scan -> scatter src ids
// ===========================================================================
__global__ void zero_kernel(int* __restrict__ p, int n) {
    int i = blockIdx.x * blockDim.x + threadIdx.x;
    if (i < n) p[i] = 0;
}

__global__ void hist_kernel(const int* __restrict__ ei, int* __restrict__ deg) {
    int e = blockIdx.x * blockDim.x + threadIdx.x;
    if (e >= N_EDGES) return;
    atomicAdd(&deg[ei[N_EDGES + e]], 1);
}

// single block, 1024 threads; rowptr[0]=0, rowptr[i+1]=incl_scan(deg)[i]
__global__ __launch_bounds__(1024) void scan_kernel(const int* __restrict__ deg,
                                                    int* __restrict__ rowptr) {
    __shared__ int buf[1024];
    __shared__ int carry_s;
    int tid = threadIdx.x;
    if (tid == 0) { carry_s = 0; rowptr[0] = 0; }
    __syncthreads();
    for (int base = 0; base < N_NODES; base += 1024) {
        int i = base + tid;
        buf[tid] = (i < N_NODES) ? deg[i] : 0;
        __syncthreads();
        for (int off = 1; off < 1024; off <<= 1) {
            int t = (tid >= off) ? buf[tid - off] : 0;
            __syncthreads();
            buf[tid] += t;
            __syncthreads();
        }
        if (i < N_NODES) rowptr[i + 1] = buf[tid] + carry_s;
        __syncthreads();
        if (tid == 0) carry_s += buf[1023];
        __syncthreads();
    }
}

__global__ void cursor_init_kernel(const int* __restrict__ rowptr,
                                   int* __restrict__ cursor) {
    int i = blockIdx.x * blockDim.x + threadIdx.x;
    if (i < N_NODES) cursor[i] = rowptr[i];
}

__global__ void scatter_kernel(const int* __restrict__ ei,
                               int* __restrict__ cursor, int* __restrict__ adj) {
    int e = blockIdx.x * blockDim.x + threadIdx.x;
    if (e >= N_EDGES) return;
    int src = ei[e], dst = ei[N_EDGES + e];
    int pos = atomicAdd(&cursor[dst], 1);
    adj[pos] = src;
}

// ===========================================================================
// Gather aggregation (CSR), fused scale + split-bf16 output.
// out[n] = (1+eps)*h[n] + sum_{k in row n} h[adj[k]]
// ===========================================================================
__global__ __launch_bounds__(256) void gather64_kernel(
    const float* __restrict__ x, const int* __restrict__ rowptr,
    const int* __restrict__ adj, const float* __restrict__ epsp,
    ushort_t* __restrict__ hi, ushort_t* __restrict__ lo) {
    int wave = threadIdx.x >> 6, lane = threadIdx.x & 63;
    int n = blockIdx.x * 4 + wave;
    if (n >= N_NODES) return;
    float s = 1.0f + *epsp;
    float sum = s * x[(size_t)n * IN_F + lane];
    int beg = rowptr[n], end = rowptr[n + 1];
    for (int k = beg; k < end; k++) {
        sum += x[(size_t)adj[k] * IN_F + lane];
    }
    ushort_t hb = f2b(sum);
    ushort_t lb = f2b(sum - b2f(hb));
    hi[(size_t)n * IN_F + lane] = hb;
    lo[(size_t)n * IN_F + lane] = lb;
}

__global__ __launch_bounds__(256) void gather512_kernel(
    const float* __restrict__ h, const int* __restrict__ rowptr,
    const int* __restrict__ adj, const float* __restrict__ epsp,
    ushort_t* __restrict__ hi, ushort_t* __restrict__ lo) {
    int wave = threadIdx.x >> 6, lane = threadIdx.x & 63;
    int n = blockIdx.x * 4 + wave;
    if (n >= N_NODES) return;
    float s = 1.0f + *epsp;
    const float* hn = h + (size_t)n * HIDDEN;
    const int f0 = lane * 4, f1 = 256 + lane * 4;
    float4 a0 = *(const float4*)&hn[f0];
    float4 a1 = *(const float4*)&hn[f1];
    float sum0[4] = {s * a0.x, s * a0.y, s * a0.z, s * a0.w};
    float sum1[4] = {s * a1.x, s * a1.y, s * a1.z, s * a1.w};
    int beg = rowptr[n], end = rowptr[n + 1];
    for (int k = beg; k < end; k++) {
        const float* hs = h + (size_t)adj[k] * HIDDEN;
        float4 b0 = *(const float4*)&hs[f0];
        float4 b1 = *(const float4*)&hs[f1];
        sum0[0] += b0.x; sum0[1] += b0.y; sum0[2] += b0.z; sum0[3] += b0.w;
        sum1[0] += b1.x; sum1[1] += b1.y; sum1[2] += b1.z; sum1[3] += b1.w;
    }
    ushort_t h4[4], l4[4];
#pragma unroll
    for (int j = 0; j < 4; j++) {
        h4[j] = f2b(sum0[j]);
        l4[j] = f2b(sum0[j] - b2f(h4[j]));
    }
    *(ushort4*)&hi[(size_t)n * HIDDEN + f0] = make_ushort4(h4[0], h4[1], h4[2], h4[3]);
    *(ushort4*)&lo[(size_t)n * HIDDEN + f0] = make_ushort4(l4[0], l4[1], l4[2], l4[3]);
#pragma unroll
    for (int j = 0; j < 4; j++) {
        h4[j] = f2b(sum1[j]);
        l4[j] = f2b(sum1[j] - b2f(h4[j]));
    }
    *(ushort4*)&hi[(size_t)n * HIDDEN + f1] = make_ushort4(h4[0], h4[1], h4[2], h4[3]);
    *(ushort4*)&lo[(size_t)n * HIDDEN + f1] = make_ushort4(l4[0], l4[1], l4[2], l4[3]);
}

// ---------------------------------------------------------------------------
// W[K][512] fp32 -> Wt_hi[512][K], Wt_lo[512][K] bf16 (transpose + split)
// ---------------------------------------------------------------------------
__global__ void wtrans_kernel(const float* __restrict__ W,
                              ushort_t* __restrict__ Whi,
                              ushort_t* __restrict__ Wlo, int K) {
    __shared__ float t[32][33];
    int tx = threadIdx.x & 31, ty = threadIdx.x >> 5;   // ty 0..7
    int nb = blockIdx.x * 32, kb = blockIdx.y * 32;
#pragma unroll
    for (int i = 0; i < 4; i++) {
        int k = kb + ty + i * 8;
        t[ty + i * 8][tx] = W[(size_t)k * HIDDEN + nb + tx];
    }
    __syncthreads();
#pragma unroll
    for (int i = 0; i < 4; i++) {
        int n = nb + ty + i * 8;
        int k = kb + tx;
        float v = t[tx][ty + i * 8];
        ushort_t hb = f2b(v);
        ushort_t lb = f2b(v - b2f(hb));
        Whi[(size_t)n * K + k] = hb;
        Wlo[(size_t)n * K + k] = lb;
    }
}

// ---------------------------------------------------------------------------
// Split-bf16 MFMA GEMM: C = epilogue(A @ B + bias), N = 512 fixed.
// 128x128 tile, BK=32, 256 threads (4 waves 2x2), 16x16x32 MFMA, 3-term split.
// 1-D grid with XCD-aware swizzle: blocks dispatch round-robin over 8 XCDs
// (b -> XCD b%8); map idx so each XCD runs one m-tile's 4 n-tiles
// back-to-back -> the 256 KB A-tile stays in that XCD's L2 (A fetched from
// HBM once instead of ~2x; reuse reads are ~200-cyc L2 hits, not ~900-cyc
// HBM misses).
// ---------------------------------------------------------------------------
__global__ __launch_bounds__(256) void gemm_split_kernel(
    const ushort_t* __restrict__ Ahi, const ushort_t* __restrict__ Alo,
    const ushort_t* __restrict__ Bhi, const ushort_t* __restrict__ Blo,
    const float* __restrict__ bias,
    float* __restrict__ Cf, ushort_t* __restrict__ Chi, ushort_t* __restrict__ Clo,
    int K, int mode,
    const float* __restrict__ bn_g, const float* __restrict__ bn_b,
    const float* __restrict__ bn_m, const float* __restrict__ bn_v) {
    __shared__ ushort_t As_h[128 * 32];
    __shared__ ushort_t As_l[128 * 32];
    __shared__ ushort_t Bs_h[128 * 32];
    __shared__ ushort_t Bs_l[128 * 32];

    const int tid  = threadIdx.x;
    const int wave = tid >> 6, lane = tid & 63;
    const int wm = wave >> 1, wn = wave & 1;
    const int quad = lane >> 4, r = lane & 15;

    // XCD-aware tile mapping
    int idx = blockIdx.x, m_t, n_t;
    if (idx < FULLGRP) {
        m_t = (idx >> 5) * 8 + (idx & 7);
        n_t = (idx >> 3) & 3;
    } else {
        int t = idx - FULLGRP;
        m_t = (FULLGRP >> 2) + (t >> 2);
        n_t = t & 3;
    }
    const int m0 = m_t * 128, n0 = n_t * 128;

    const f32x4 vzero = {0.f, 0.f, 0.f, 0.f};
    f32x4 acc[4][4];
#pragma unroll
    for (int i = 0; i < 4; i++)
#pragma unroll
        for (int j = 0; j < 4; j++) acc[i][j] = vzero;

    const int srow = (lane >> 2);          // 0..15
    const int scol = (lane & 3) * 8;       // 8 bf16 = 16 B

    for (int k0 = 0; k0 < K; k0 += 32) {
        __syncthreads();
#pragma unroll
        for (int t = 0; t < 2; t++) {
            int rr = wave * 32 + t * 16 + srow;
            int lbase = (wave * 32 + t * 16) * 32;
            size_t ga = (size_t)(m0 + rr) * K + k0 + scol;
            size_t gb = (size_t)(n0 + rr) * K + k0 + scol;
            async_copy16(Ahi + ga, &As_h[lbase]);
            async_copy16(Alo + ga, &As_l[lbase]);
            async_copy16(Bhi + gb, &Bs_h[lbase]);
            async_copy16(Blo + gb, &Bs_l[lbase]);
        }
        __syncthreads();

        bf16x8 ah[4], al[4], bh[4], bl[4];
#pragma unroll
        for (int i = 0; i < 4; i++) {
            int aofs = (wm * 64 + i * 16 + r) * 32 + quad * 8;
            int bofs = (wn * 64 + i * 16 + r) * 32 + quad * 8;
            ah[i] = *(const bf16x8*)&As_h[aofs];
            al[i] = *(const bf16x8*)&As_l[aofs];
            bh[i] = *(const bf16x8*)&Bs_h[bofs];
            bl[i] = *(const bf16x8*)&Bs_l[bofs];
        }
#pragma unroll
        for (int i = 0; i < 4; i++)
#pragma unroll
            for (int j = 0; j < 4; j++) {
                acc[i][j] = __builtin_amdgcn_mfma_f32_16x16x32_bf16(ah[i], bh[j], acc[i][j], 0, 0, 0);
                acc[i][j] = __builtin_amdgcn_mfma_f32_16x16x32_bf16(ah[i], bl[j], acc[i][j], 0, 0, 0);
                acc[i][j] = __builtin_amdgcn_mfma_f32_16x16x32_bf16(al[i], bh[j], acc[i][j], 0, 0, 0);
            }
    }

    float bia[4], sc[4], sh[4];
#pragma unroll
    for (int j = 0; j < 4; j++) {
        int col = n0 + wn * 64 + j * 16 + r;
        bia[j] = bias[col];
        if (mode == 2) {
            float g = bn_g[col], bb = bn_b[col], mm = bn_m[col], vv = bn_v[col];
            sc[j] = g * rsqrtf(vv + BN_EPS);
            sh[j] = bb - mm * sc[j];
        } else { sc[j] = 1.f; sh[j] = 0.f; }
    }
#pragma unroll
    for (int i = 0; i < 4; i++) {
#pragma unroll
        for (int rg = 0; rg < 4; rg++) {
            int row = m0 + wm * 64 + i * 16 + quad * 4 + rg;
            if (row >= N_NODES) continue;
#pragma unroll
            for (int j = 0; j < 4; j++) {
                int col = n0 + wn * 64 + j * 16 + r;
                float v = acc[i][j][rg] + bia[j];
                if (mode >= 1) v = fmaxf(v, 0.f);
                if (mode == 2) v = v * sc[j] + sh[j];
                size_t idx2 = (size_t)row * HIDDEN + col;
                if (Cf) {
                    Cf[idx2] = v;
                } else {
                    ushort_t hb = f2b(v);
                    ushort_t lb = f2b(v - b2f(hb));
                    Chi[idx2] = hb;
                    Clo[idx2] = lb;
                }
            }
        }
    }
}

// ---------------------------------------------------------------------------
// out[t] = (h[a_t] * h[b_t]) @ fc2_W + fc2_b ; one wave per train edge.
// ---------------------------------------------------------------------------
__global__ __launch_bounds__(256) void fc2_kernel(
    const float* __restrict__ h, const int* __restrict__ ei,
    const int* __restrict__ teid, const float* __restrict__ W,
    const float* __restrict__ bias, float* __restrict__ out) {
    __shared__ float Ws[HIDDEN * N_CLASS];
    __shared__ float bs[N_CLASS];
    for (int i = threadIdx.x; i < HIDDEN * N_CLASS; i += blockDim.x) Ws[i] = W[i];
    if (threadIdx.x < N_CLASS) bs[threadIdx.x] = bias[threadIdx.x];
    __syncthreads();

    int wave = threadIdx.x >> 6;
    int lane = threadIdx.x & 63;
    int t = blockIdx.x * 4 + wave;
    if (t >= N_TRAIN) return;

    int e = teid[t];
    int a = ei[e];
    int b = ei[N_EDGES + e];
    const float* xa = h + (size_t)a * HIDDEN;
    const float* xb = h + (size_t)b * HIDDEN;

    float acc[N_CLASS];
#pragma unroll
    for (int c = 0; c < N_CLASS; c++) acc[c] = 0.f;

    int j0 = lane * 8;
    float4 a0 = *(const float4*)&xa[j0];
    float4 a1 = *(const float4*)&xa[j0 + 4];
    float4 b0 = *(const float4*)&xb[j0];
    float4 b1 = *(const float4*)&xb[j0 + 4];
    float p[8] = {a0.x * b0.x, a0.y * b0.y, a0.z * b0.z, a0.w * b0.w,
                  a1.x * b1.x, a1.y * b1.y, a1.z * b1.z, a1.w * b1.w};
#pragma unroll
    for (int jj = 0; jj < 8; jj++) {
        const float* wrow = &Ws[(j0 + jj) * N_CLASS];
#pragma unroll
        for (int c = 0; c < N_CLASS; c++) acc[c] = fmaf(p[jj], wrow[c], acc[c]);
    }
#pragma unroll
    for (int c = 0; c < N_CLASS; c++) {
        float v = acc[c];
        for (int off = 32; off > 0; off >>= 1) v += __shfl_down(v, off, 64);
        if (lane == 0) out[(size_t)t * N_CLASS + c] = v + bs[c];
    }
}

// ---------------------------------------------------------------------------
// Workspace (~211.4 MB):
//   R0h R0l R1h R1l (4 bf16 planes) | weights | CSR {deg/cursor, rowptr, adj}
// Liveness chain:
//   gather64 -> H0 split (head of R1)          [x input]
//   gemm1: H0 -> h1 split (R0)
//   gemm2: R0 -> h2 split (R1, kills H0)
//   gemm3: R1 -> h3 fp32  (F32_R0, kills h1)
//   gather512: F32_R0 -> h4 split (R1, kills h2)
//   gemm4: R1 -> h5 split (R0, kills h3)
//   gemm5: R0 -> h6 split (R1, kills h4)
//   gemm6: R1 -> h7 fp32  (F32_R0, kills h5)
//   fc2:   F32_R0 -> out
// ---------------------------------------------------------------------------
extern "C" void kernel_launch(void* const* d_in, const int* in_sizes, int n_in,
                              void* d_out, int out_size, void* d_ws, size_t ws_size,
                              hipStream_t stream) {
    const float* x      = (const float*)d_in[0];
    const int*   ei     = (const int*)d_in[1];
    const int*   teid   = (const int*)d_in[2];
    const float* W1     = (const float*)d_in[3];
    const float* b1     = (const float*)d_in[4];
    const float* W2     = (const float*)d_in[5];
    const float* b2     = (const float*)d_in[6];
    const float* W3     = (const float*)d_in[7];
    const float* b3     = (const float*)d_in[8];
    const float* bn1_g  = (const float*)d_in[9];
    const float* bn1_b  = (const float*)d_in[10];
    const float* bn1_m  = (const float*)d_in[11];
    const float* bn1_v  = (const float*)d_in[12];
    const float* eps1   = (const float*)d_in[13];
    const float* W4     = (const float*)d_in[14];
    const float* b4     = (const float*)d_in[15];
    const float* bn2_g  = (const float*)d_in[16];
    const float* bn2_b  = (const float*)d_in[17];
    const float* bn2_m  = (const float*)d_in[18];
    const float* bn2_v  = (const float*)d_in[19];
    const float* eps2   = (const float*)d_in[20];
    const float* lin1_W = (const float*)d_in[21];
    const float* lin1_b = (const float*)d_in[22];
    const float* lin2_W = (const float*)d_in[23];
    const float* lin2_b = (const float*)d_in[24];
    const float* fc2_W  = (const float*)d_in[25];
    const float* fc2_b  = (const float*)d_in[26];

    const size_t PLANE   = (size_t)MPAD * HIDDEN;
    const size_t PLANE64 = (size_t)MPAD * IN_F;

    ushort_t* R0h = (ushort_t*)d_ws;
    ushort_t* R0l = R0h + PLANE;
    ushort_t* R1h = R0l + PLANE;
    ushort_t* R1l = R1h + PLANE;

    const size_t WSMALL = (size_t)HIDDEN * IN_F;
    const size_t WBIG   = (size_t)HIDDEN * HIDDEN;
    ushort_t* Wp   = R1l + PLANE;
    ushort_t* Wt1h = Wp;            ushort_t* Wt1l = Wt1h + WSMALL;
    ushort_t* Wt2h = Wt1l + WSMALL; ushort_t* Wt2l = Wt2h + WBIG;
    ushort_t* Wt3h = Wt2l + WBIG;   ushort_t* Wt3l = Wt3h + WBIG;
    ushort_t* Wt4h = Wt3l + WBIG;   ushort_t* Wt4l = Wt4h + WBIG;
    ushort_t* Wt5h = Wt4l + WBIG;   ushort_t* Wt5l = Wt5h + WBIG;
    ushort_t* Wt6h = Wt5l + WBIG;   ushort_t* Wt6l = Wt6h + WBIG;

    // CSR arrays (ints) after weights
    int* deg    = (int*)(Wt6l + WBIG);   // also scatter cursor
    int* rowptr = deg + N_NODES;         // N_NODES + 1
    int* adj    = rowptr + (N_NODES + 1);

    // fp32 aliases
    float* F32_R0 = (float*)R0h;
    // H0 split planes at head of R1 region
    ushort_t* H0h = R1h;
    ushort_t* H0l = R1h + PLANE64;

    // ---- CSR build ----
    zero_kernel<<<(N_NODES + 255) / 256, 256, 0, stream>>>(deg, N_NODES);
    hist_kernel<<<(N_EDGES + 255) / 256, 256, 0, stream>>>(ei, deg);
    scan_kernel<<<1, 1024, 0, stream>>>(deg, rowptr);
    cursor_init_kernel<<<(N_NODES + 255) / 256, 256, 0, stream>>>(rowptr, deg);
    scatter_kernel<<<(N_EDGES + 255) / 256, 256, 0, stream>>>(ei, deg, adj);

    // ---- weight prep: transpose + split ----
    dim3 wtgS(HIDDEN / 32, IN_F / 32);
    dim3 wtgB(HIDDEN / 32, HIDDEN / 32);
    wtrans_kernel<<<wtgS, 256, 0, stream>>>(W1, Wt1h, Wt1l, IN_F);
    wtrans_kernel<<<wtgB, 256, 0, stream>>>(W2, Wt2h, Wt2l, HIDDEN);
    wtrans_kernel<<<wtgB, 256, 0, stream>>>(W3, Wt3h, Wt3l, HIDDEN);
    wtrans_kernel<<<wtgB, 256, 0, stream>>>(W4, Wt4h, Wt4l, HIDDEN);
    wtrans_kernel<<<wtgB, 256, 0, stream>>>(lin1_W, Wt5h, Wt5l, HIDDEN);
    wtrans_kernel<<<wtgB, 256, 0, stream>>>(lin2_W, Wt6h, Wt6l, HIDDEN);

    const int ngrid = MT * NT;     // 1564 blocks, 1-D swizzled grid
    int nwb = (N_NODES + 3) / 4;   // wave-per-node blocks (4 waves/block)

    // ---- h0 = (1+eps1)*x + gather(x) -> H0 split ----
    gather64_kernel<<<nwb, 256, 0, stream>>>(x, rowptr, adj, eps1, H0h, H0l);

    // h1 = relu(h0 @ W1 + b1) -> R0 split
    gemm_split_kernel<<<ngrid, 256, 0, stream>>>(H0h, H0l, Wt1h, Wt1l, b1,
        nullptr, R0h, R0l, IN_F, 1, nullptr, nullptr, nullptr, nullptr);
    // h2 = relu(h1 @ W2 + b2) -> R1 split
    gemm_split_kernel<<<ngrid, 256, 0, stream>>>(R0h, R0l, Wt2h, Wt2l, b2,
        nullptr, R1h, R1l, HIDDEN, 1, nullptr, nullptr, nullptr, nullptr);
    // h3 = bn1(relu(h2 @ W3 + b3)) -> F32_R0
    gemm_split_kernel<<<ngrid, 256, 0, stream>>>(R1h, R1l, Wt3h, Wt3l, b3,
        F32_R0, nullptr, nullptr, HIDDEN, 2, bn1_g, bn1_b, bn1_m, bn1_v);

    // ---- h4 = (1+eps2)*h3 + gather(h3) -> R1 split ----
    gather512_kernel<<<nwb, 256, 0, stream>>>(F32_R0, rowptr, adj, eps2, R1h, R1l);

    // h5 = bn2(relu(h4 @ W4 + b4)) -> R0 split
    gemm_split_kernel<<<ngrid, 256, 0, stream>>>(R1h, R1l, Wt4h, Wt4l, b4,
        nullptr, R0h, R0l, HIDDEN, 2, bn2_g, bn2_b, bn2_m, bn2_v);
    // h6 = relu(h5 @ lin1_W + lin1_b) -> R1 split
    gemm_split_kernel<<<ngrid, 256, 0, stream>>>(R0h, R0l, Wt5h, Wt5l, lin1_b,
        nullptr, R1h, R1l, HIDDEN, 1, nullptr, nullptr, nullptr, nullptr);
    // h7 = h6 @ lin2_W + lin2_b -> F32_R0
    gemm_split_kernel<<<ngrid, 256, 0, stream>>>(R1h, R1l, Wt6h, Wt6l, lin2_b,
        F32_R0, nullptr, nullptr, HIDDEN, 0, nullptr, nullptr, nullptr, nullptr);

    // head
    fc2_kernel<<<(N_TRAIN + 3) / 4, 256, 0, stream>>>(F32_R0, ei, teid, fc2_W, fc2_b,
                                                      (float*)d_out);
}